// Round 7
// baseline (291.990 us; speedup 1.0000x reference)
//
#include <hip/hip_runtime.h>
#include <math.h>

// Problem constants (fixed by setup_inputs)
#define BB 72      // G * SAMPLE_NUMS = 8*9
#define SS 512
#define HH 768
#define GG 8
#define SN 9
#define VR 2       // VIEW_RANGE
#define NT 16      // distinct turn values (randint(0,16))
#define NPART 16   // cross-num partials per batch (one per k_ct block)

// Output is FP32, layout = return order [loss | q | a | n] (verified).
// Inputs fp32, dict order.
//
// Bucket factorization (verified round 2): band(t) depends only on v=turn_t:
//   G_i^(u)[h] = sum_{turn_s=u, id_s=i} am_s^2 x_s[h]      (k_g, one x pass)
//   W_i^(v)    = sum_{u in [v-2,v+2]} G_i^(u)              (k_w, G read once)
//   d_i(t)     = x_t . W_i^(turn_t)                        (k_ct, one x pass)
// Round 17: materialize W in k_w (kills ~830 MB of repeated window gathers in
// k_ct); k_ct LDS 37->9 KB via single ds_add-reduced buffer (residency up);
// k_g preloads only tn + its run segment, 8-deep row batching.

__device__ float g_G [(size_t)BB * NT * 4 * HH];       // 14.2 MB
__device__ float g_Wm[(size_t)BB * NT * 4 * HH];       // 14.2 MB (windowed)
__device__ float g_xpart[(size_t)BB * NPART * 3 * HH]; // cross-num block partials
__device__ float g_logits[3 * BB];

__device__ __forceinline__ void class_masks(float am, int id, float& qv, float& av, float& nv) {
    qv = (id == 1 || id == 2) ? am : 0.0f;
    av = (id == 0 || id == 2) ? am : 0.0f;
    nv = (id == 3) ? am : 0.0f;
}

// ---------------------------------------------------------------------------
// k_g: grid (NT, BB), block 192 (thread owns h = tid*4 + {0..3}).
// Block (u,b): binary-search run [beg,end) over LDS tn; coalesce-load the
// run's am/qa segment; sum am^2 * x rows id-split into 4 float4 register
// accumulators (block-uniform branches); write G[b][u] once (empty -> zeros).
// 8-deep guarded row batches for MLP (~24 KB in flight).
// ---------------------------------------------------------------------------
__global__ __launch_bounds__(192) void k_g(const float* __restrict__ x,
                                           const float* __restrict__ am,
                                           const int* __restrict__ qa,
                                           const int* __restrict__ turn) {
    __shared__ int   tn[SS];
    __shared__ float c2[SS];
    __shared__ int   idv[SS];

    const int u = blockIdx.x, b = blockIdx.y;
    const int tid = threadIdx.x;

    for (int i = tid; i < SS; i += 192) tn[i] = turn[b * SS + i];
    __syncthreads();

    // run bounds: [beg, end) with tn == u  (tn sorted ascending)
    int L = 0, R = SS;
    while (L < R) { int m = (L + R) >> 1; if (tn[m] < u) L = m + 1; else R = m; }
    const int beg = L;
    L = beg; R = SS;
    while (L < R) { int m = (L + R) >> 1; if (tn[m] <= u) L = m + 1; else R = m; }
    const int end = L;

    // preload only the run's am/qa segment
    for (int i = beg + tid; i < end; i += 192) {
        float a = am[b * SS + i]; c2[i] = a * a;
        idv[i] = qa[b * SS + i];
    }
    __syncthreads();

    float4 acc[4];
#pragma unroll
    for (int i = 0; i < 4; ++i) acc[i] = make_float4(0.f, 0.f, 0.f, 0.f);

    const float* xb = x + (size_t)b * SS * HH + tid * 4;
    for (int s = beg; s < end; s += 8) {
        float4 v[8];
#pragma unroll
        for (int k = 0; k < 8; ++k) {
            const int ss = s + k;
            v[k] = (ss < end) ? *(const float4*)(xb + (size_t)ss * HH)
                              : make_float4(0.f, 0.f, 0.f, 0.f);
        }
#pragma unroll
        for (int k = 0; k < 8; ++k) {
            const int ss = s + k;
            if (ss < end) {                       // block-uniform
                const float cc = c2[ss];
                const int id = idv[ss];           // block-uniform
                const float4 xv = v[k];
                if (id == 0) { acc[0].x += xv.x * cc; acc[0].y += xv.y * cc;
                               acc[0].z += xv.z * cc; acc[0].w += xv.w * cc; }
                else if (id == 1) { acc[1].x += xv.x * cc; acc[1].y += xv.y * cc;
                                    acc[1].z += xv.z * cc; acc[1].w += xv.w * cc; }
                else if (id == 2) { acc[2].x += xv.x * cc; acc[2].y += xv.y * cc;
                                    acc[2].z += xv.z * cc; acc[2].w += xv.w * cc; }
                else { acc[3].x += xv.x * cc; acc[3].y += xv.y * cc;
                       acc[3].z += xv.z * cc; acc[3].w += xv.w * cc; }
            }
        }
    }

    float* go = g_G + ((size_t)(b * NT + u) * 4) * HH + tid * 4;
#pragma unroll
    for (int i = 0; i < 4; ++i)
        *(float4*)(go + (size_t)i * HH) = acc[i];
}

// ---------------------------------------------------------------------------
// k_w: W[b][v] = sum_{u in [v-2,v+2]} G[b][u]. grid (4, BB): block owns a
// 192-float h-quarter; stages G[b][*][*][quarter] (48 KB) in LDS once, emits
// all 16 windowed buckets. G read exactly once chip-wide.
// ---------------------------------------------------------------------------
__global__ __launch_bounds__(256) void k_w() {
    __shared__ float Gl[NT * 4 * 192];   // 48 KB
    const int qh = blockIdx.x, b = blockIdx.y, tid = threadIdx.x;

    for (int idx = tid * 4; idx < NT * 4 * 192; idx += 1024) {
        const int u = idx / 768, rem = idx % 768;
        const int i = rem / 192, hh = rem % 192;
        *(float4*)&Gl[idx] =
            *(const float4*)(g_G + ((size_t)(b * NT + u) * 4 + i) * HH + qh * 192 + hh);
    }
    __syncthreads();

    for (int idx = tid * 4; idx < NT * 4 * 192; idx += 1024) {
        const int v = idx / 768, rem = idx % 768;
        const int i = rem / 192, hh = rem % 192;
        const int ulo = (v - VR < 0) ? 0 : v - VR;
        const int uhi = (v + VR > NT - 1) ? NT - 1 : v + VR;
        float4 s = make_float4(0.f, 0.f, 0.f, 0.f);
        for (int u = ulo; u <= uhi; ++u) {
            const float4 gv = *(const float4*)&Gl[(u * 4 + i) * 192 + hh];
            s.x += gv.x; s.y += gv.y; s.z += gv.z; s.w += gv.w;
        }
        *(float4*)(g_Wm + ((size_t)(b * NT + v) * 4 + i) * HH + qh * 192 + hh) = s;
    }
}

// ---------------------------------------------------------------------------
// k_ct: per t: d_i = x_t . W_i^(turn_t), W loaded directly from g_Wm per
// v-change (12 float4, L2/L3-hot). All 8 t-rows prefetched to registers.
// Epilogue algebra -> cw_{q,a,n}(t); cross numerators accumulated in
// registers; block reduce via single 9 KB LDS buffer + ds_add (NPART=16).
// grid (SS/32=16, BB), block 256 = 4 waves; wave owns 8 t's; lane owns
// h = ch*256 + lane*4 + {0..3}, ch = 0..2.
// ---------------------------------------------------------------------------
__global__ __launch_bounds__(256) void k_ct(const float* __restrict__ x,
                                            const float* __restrict__ am,
                                            const int* __restrict__ qa,
                                            const int* __restrict__ turn) {
    __shared__ float red[3 * HH];      // 9 KB
    __shared__ int   tnb[32];
    __shared__ float amb[32];
    __shared__ int   idb[32];

    const int b = blockIdx.y, ts = blockIdx.x, T0 = ts * 32;
    const int tid = threadIdx.x, w = tid >> 6, lane = tid & 63;
    if (tid < 32) {
        tnb[tid] = turn[b * SS + T0 + tid];
        amb[tid] = am[b * SS + T0 + tid];
        idb[tid] = qa[b * SS + T0 + tid];
    }
    for (int idx = tid; idx < 3 * HH; idx += 256) red[idx] = 0.0f;
    __syncthreads();

    const float* xb = x + (size_t)b * SS * HH;
    float4 xt[8][3];
#pragma unroll
    for (int it = 0; it < 8; ++it) {
        const float* xr = xb + (size_t)(T0 + w * 8 + it) * HH + lane * 4;
        xt[it][0] = *(const float4*)(xr + 0);
        xt[it][1] = *(const float4*)(xr + 256);
        xt[it][2] = *(const float4*)(xr + 512);
    }

    float xn[3][12];
#pragma unroll
    for (int c = 0; c < 3; ++c)
#pragma unroll
        for (int k = 0; k < 12; ++k) xn[c][k] = 0.0f;

    float4 Wr[4][3];
    int curv = -1;

#pragma unroll
    for (int it = 0; it < 8; ++it) {
        const int tl = w * 8 + it;
        const int v = tnb[tl];                 // wave-uniform
        if (v != curv) {
            curv = v;
            const float* Wg = g_Wm + ((size_t)(b * NT + v) * 4) * HH + lane * 4;
#pragma unroll
            for (int i = 0; i < 4; ++i) {
                Wr[i][0] = *(const float4*)(Wg + (size_t)i * HH + 0);
                Wr[i][1] = *(const float4*)(Wg + (size_t)i * HH + 256);
                Wr[i][2] = *(const float4*)(Wg + (size_t)i * HH + 512);
            }
        }
        float d[4];
#pragma unroll
        for (int i = 0; i < 4; ++i) {
            float s = 0;
#pragma unroll
            for (int ch = 0; ch < 3; ++ch) {
                s += xt[it][ch].x * Wr[i][ch].x + xt[it][ch].y * Wr[i][ch].y
                   + xt[it][ch].z * Wr[i][ch].z + xt[it][ch].w * Wr[i][ch].w;
            }
            d[i] = s;
        }
#pragma unroll
        for (int off = 32; off; off >>= 1) {
#pragma unroll
            for (int i = 0; i < 4; ++i) d[i] += __shfl_xor(d[i], off);
        }
        float qt, at, nt; class_masks(amb[tl], idb[tl], qt, at, nt);
        const float ant = at + nt, qnt = qt + nt, qat = qt + at;
        const float Sqq = d[1] + d[2], Sqa = d[2], Saa = d[0] + d[2], Snn = d[3];
        const float cwq = qt * (ant * Sqa + qnt * Saa + qat * Snn);
        const float cwa = at * (ant * Sqq + qnt * Sqa + qat * Snn);
        const float cwn = nt * (ant * (Sqq + Sqa) + qnt * (Sqa + Saa));
#pragma unroll
        for (int ch = 0; ch < 3; ++ch) {
            const float4 xv = xt[it][ch];
            xn[0][ch * 4 + 0] += cwq * xv.x; xn[0][ch * 4 + 1] += cwq * xv.y;
            xn[0][ch * 4 + 2] += cwq * xv.z; xn[0][ch * 4 + 3] += cwq * xv.w;
            xn[1][ch * 4 + 0] += cwa * xv.x; xn[1][ch * 4 + 1] += cwa * xv.y;
            xn[1][ch * 4 + 2] += cwa * xv.z; xn[1][ch * 4 + 3] += cwa * xv.w;
            xn[2][ch * 4 + 0] += cwn * xv.x; xn[2][ch * 4 + 1] += cwn * xv.y;
            xn[2][ch * 4 + 2] += cwn * xv.z; xn[2][ch * 4 + 3] += cwn * xv.w;
        }
    }

    // block reduce: 4 waves ds_add into one buffer (lane-parallel, distinct
    // addresses within a wave; 4-way cross-wave collision per address)
#pragma unroll
    for (int c = 0; c < 3; ++c)
#pragma unroll
        for (int ch = 0; ch < 3; ++ch)
#pragma unroll
            for (int k = 0; k < 4; ++k)
                atomicAdd(&red[c * HH + ch * 256 + lane * 4 + k], xn[c][ch * 4 + k]);
    __syncthreads();

    float* xo = g_xpart + (size_t)(b * NPART + ts) * 3 * HH;
    for (int idx = tid * 4; idx < 3 * HH; idx += 1024)
        *(float4*)(xo + idx) = *(float4*)&red[idx];
}

// ---------------------------------------------------------------------------
// k_cos: dens + cosine logits per class c; self numerators derived from G
// column sums (sq = T1+T2, sa = T0+T2, sn = T3); fp32 self-avg outputs for
// group sample 0 at out[1 + (c*GG + g)*HH + h]. grid (3, BB), block 256.
// ---------------------------------------------------------------------------
__global__ void k_cos(const float* __restrict__ am, const int* __restrict__ qa,
                      float* __restrict__ out) {
    const int c = blockIdx.x, b = blockIdx.y, tid = threadIdx.x;
    const int wave = tid >> 6, lane = tid & 63;
    __shared__ float redd[4][3];
    __shared__ float sD[3];

    float q = 0, a = 0, n = 0;
    for (int s = tid; s < SS; s += 256) {
        float m = am[b * SS + s]; int id = qa[b * SS + s];
        float qv, av, nv; class_masks(m, id, qv, av, nv);
        q += qv; a += av; n += nv;
    }
#pragma unroll
    for (int off = 32; off; off >>= 1) {
        q += __shfl_down(q, off); a += __shfl_down(a, off); n += __shfl_down(n, off);
    }
    if (lane == 0) { redd[wave][0] = q; redd[wave][1] = a; redd[wave][2] = n; }
    __syncthreads();
    if (tid == 0) {
        float Q = 0, A = 0, N = 0;
#pragma unroll
        for (int w = 0; w < 4; ++w) { Q += redd[w][0]; A += redd[w][1]; N += redd[w][2]; }
        sD[0] = Q; sD[1] = A; sD[2] = N;
    }
    __syncthreads();
    const float Dq = sD[0], Da = sD[1], Dn = sD[2];
    const float Dself = (c == 0) ? Dq : ((c == 1) ? Da : Dn);
    const float Dcross = (c == 0) ? (Da + Dn) : ((c == 1) ? (Dq + Dn) : (Dq + Da));
    const float invS = 1.0f / (Dself + 1e-6f), invC = 1.0f / (Dcross + 1e-6f);

    float dot = 0, n1 = 0, n2 = 0;
#pragma unroll
    for (int j = 0; j < 3; ++j) {
        const int h = tid + j * 256;
        // self numerator from G column sums
        const float* Gb = g_G + ((size_t)b * NT * 4) * HH + h;
        float sv = 0;
        if (c == 0) {
            for (int u = 0; u < NT; ++u)
                sv += Gb[(size_t)(u * 4 + 1) * HH] + Gb[(size_t)(u * 4 + 2) * HH];
        } else if (c == 1) {
            for (int u = 0; u < NT; ++u)
                sv += Gb[(size_t)(u * 4 + 0) * HH] + Gb[(size_t)(u * 4 + 2) * HH];
        } else {
            for (int u = 0; u < NT; ++u)
                sv += Gb[(size_t)(u * 4 + 3) * HH];
        }
        float cv = 0;
        const float* xp = g_xpart + ((size_t)b * NPART * 3 + c) * HH + h;
#pragma unroll
        for (int p = 0; p < NPART; ++p) cv += xp[(size_t)p * 3 * HH];
        sv *= invS; cv *= invC;
        dot += sv * cv; n1 += sv * sv; n2 += cv * cv;
        if (b % SN == 0)
            out[1 + ((size_t)c * GG + b / SN) * HH + h] = sv;
    }
#pragma unroll
    for (int off = 32; off; off >>= 1) {
        dot += __shfl_down(dot, off); n1 += __shfl_down(n1, off); n2 += __shfl_down(n2, off);
    }
    __shared__ float red2[4][3];
    if (lane == 0) { red2[wave][0] = dot; red2[wave][1] = n1; red2[wave][2] = n2; }
    __syncthreads();
    if (tid == 0) {
        float D = 0, N1 = 0, N2 = 0;
#pragma unroll
        for (int w = 0; w < 4; ++w) { D += red2[w][0]; N1 += red2[w][1]; N2 += red2[w][2]; }
        float nx = fmaxf(sqrtf(N1), 1e-8f);
        float ny = fmaxf(sqrtf(N2), 1e-8f);
        float cc = D / (nx * ny);
        if (cc == 1.0f) cc = __uint_as_float(0x7FC00000u);
        g_logits[c * BB + b] = cc / 0.07f;
    }
}

// log_softmax + nanmean loss across 3 classes -> out[0] (fp32). (unchanged)
__global__ void k_loss(const float* __restrict__ labels, float* __restrict__ out) {
    __shared__ float rs[24];
    __shared__ int rc[24];
    const int tid = threadIdx.x;
    if (tid < 24) {
        int c = tid / GG, g = tid % GG;
        float lg[SN]; bool anynan = false;
        for (int j = 0; j < SN; ++j) {
            float v = g_logits[c * BB + g * SN + j];
            lg[j] = v;
            anynan = anynan || isnan(v);
        }
        float ssum = 0; int cnt = 0;
        if (!anynan) {
            float m = -1e30f;
            for (int j = 0; j < SN; ++j) m = fmaxf(m, lg[j]);
            float se = 0;
            for (int j = 0; j < SN; ++j) se += expf(lg[j] - m);
            float lse = m + logf(se);
            for (int j = 0; j < SN; ++j) ssum += (lg[j] - lse) * labels[g * SN + j];
            cnt = SN;
        }
        rs[tid] = ssum; rc[tid] = cnt;
    }
    __syncthreads();
    if (tid == 0) {
        float total = 0;
        for (int c = 0; c < 3; ++c) {
            float s = 0; int n = 0;
            for (int g = 0; g < GG; ++g) { s += rs[c * GG + g]; n += rc[c * GG + g]; }
            total += -(s / (float)n);
        }
        out[0] = total / 3.0f;
    }
}

extern "C" void kernel_launch(void* const* d_in, const int* in_sizes, int n_in,
                              void* d_out, int out_size, void* d_ws, size_t ws_size,
                              hipStream_t stream) {
    const float* x      = (const float*)d_in[0];
    const float* am     = (const float*)d_in[1];
    const float* labels = (const float*)d_in[2];
    const int*   qa     = (const int*)d_in[3];
    const int*   turn   = (const int*)d_in[4];
    float* out = (float*)d_out;

    k_g   <<<dim3(NT, BB),      192, 0, stream>>>(x, am, qa, turn);
    k_w   <<<dim3(4, BB),       256, 0, stream>>>();
    k_ct  <<<dim3(SS / 32, BB), 256, 0, stream>>>(x, am, qa, turn);
    k_cos <<<dim3(3, BB),       256, 0, stream>>>(am, qa, out);
    k_loss<<<dim3(1),           64,  0, stream>>>(labels, out);
}